// Round 6
// baseline (551.915 us; speedup 1.0000x reference)
//
#include <hip/hip_runtime.h>

typedef __attribute__((ext_vector_type(8)))  __bf16 bf16x8;
typedef __attribute__((ext_vector_type(16))) float  f32x16;
typedef __attribute__((ext_vector_type(4)))  float  f32x4;
typedef __attribute__((ext_vector_type(8)))  unsigned short u16x8;

// ---------- fp32 -> bf16 (RNE) ----------
__device__ inline unsigned short f2bf(float f) {
    unsigned int u = __float_as_uint(f);
    u += 0x7FFFu + ((u >> 16) & 1u);
    return (unsigned short)(u >> 16);
}

// ============================================================================
// Fused scatter (COO -> bf16 dense) + weight fp32->bf16 convert. (unchanged)
// ============================================================================
__global__ __launch_bounds__(256) void scatter_cvt(
        const float* __restrict__ vals,
        const int* __restrict__ rows,
        const int* __restrict__ cols,
        unsigned short* __restrict__ Ab,
        int nnz, int in_f,
        const float* __restrict__ wsrc,
        unsigned short* __restrict__ wdst,
        long nW, int cvtBlocks) {
    if ((int)blockIdx.x < cvtBlocks) {
        long i = ((long)blockIdx.x * 256 + threadIdx.x) * 8;
        if (i + 8 <= nW) {
            f32x4 a = *(const f32x4*)(wsrc + i);
            f32x4 b = *(const f32x4*)(wsrc + i + 4);
            u16x8 o;
            o[0] = f2bf(a[0]); o[1] = f2bf(a[1]); o[2] = f2bf(a[2]); o[3] = f2bf(a[3]);
            o[4] = f2bf(b[0]); o[5] = f2bf(b[1]); o[6] = f2bf(b[2]); o[7] = f2bf(b[3]);
            *(u16x8*)(wdst + i) = o;
        }
        return;
    }
    int i = ((int)blockIdx.x - cvtBlocks) * 256 + threadIdx.x;
    if (i >= nnz) return;
    float v = vals[i];
    size_t idx = (size_t)rows[i] * in_f + cols[i];
#if __has_builtin(__builtin_amdgcn_global_atomic_fadd_v2bf16)
    typedef __attribute__((ext_vector_type(2))) short s16x2;
    unsigned short hv = f2bf(v);
    s16x2 add;
    add[0] = (idx & 1) ? (short)0 : (short)hv;
    add[1] = (idx & 1) ? (short)hv : (short)0;
    __builtin_amdgcn_global_atomic_fadd_v2bf16(
        (__attribute__((address_space(1))) s16x2*)(Ab + (idx & ~(size_t)1)), add);
#else
    unsigned int* word = (unsigned int*)(Ab + (idx & ~(size_t)1));
    unsigned int sh = (unsigned int)(idx & 1) * 16u;
    unsigned int old = *word, assumed;
    do {
        assumed = old;
        unsigned int cur = (assumed >> sh) & 0xFFFFu;
        float f = __uint_as_float(cur << 16) + v;
        unsigned int nb = f2bf(f);
        unsigned int repl = (assumed & ~(0xFFFFu << sh)) | (nb << sh);
        old = atomicCAS(word, assumed, repl);
    } while (old != assumed);
#endif
}

// ============================================================================
// bf16 NT GEMM, 256x256 tile, BK=64, 8 waves (2M x 4N), 32x32x16 MFMA,
// 1 barrier/tile, REGISTER-PIPELINED fragments (X/Y double buffer).
//
// R5 post-mortem: barrier count and bank conflicts both proven non-binding
// (R4 0-conflict/8-barrier == R5 25M/1-barrier == ~5000 cyc/tile vs 2065
// MFMA floor).  Binding constraint: ds_read latency exposed inside each
// phase (reads immediately consumed by MFMA; 2 waves/SIMD in lockstep have
// nothing to hide it).  Fix: each phase issues the NEXT chunk's 12 ds_reads,
// then runs MFMA on the PREVIOUS set — LDS latency hides under 129 cyc of
// MFMA issue; compiler's precise per-register lgkm waits become counted
// (12 outstanding) automatically.
//
// Per K-tile t (cur=t&1):
//  ph0: issue Y-reads (tile t, ch1=k32..63, buf[cur])   | MFMA(X: t ch0)
//  ph1: vmcnt(0)+lgkmcnt(0); sched_barrier; s_barrier;
//       issue X-reads (tile t+1, ch0, buf[nxt])
//       stage buf[cur] <- tile t+2 (8 gload_lds)        | MFMA(Y: t ch1)
//
// Hazard ledger (all waves):
//  - buf[cur] overwrite (stage, post-barrier) vs reads of buf[cur] (Y,
//    issued ph0): every wave drains lgkmcnt(0) BEFORE the barrier => all
//    Y-reads returned before any DMA-write issues.  OK.
//  - X-reads of buf[nxt] (post-barrier) vs its staging DMAs (issued at
//    t-1 ph1): every wave vmcnt(0)-drains own DMAs before the barrier. OK.
//  - buf[nxt] next overwrite is t+1 ph1 post-barrier, and this tile's
//    X-reads are lgkm-drained at t+1 ph1's gate (pre-barrier).  OK.
//  - vmcnt(0) slack: DMAs issued t-1 ph1 post-barrier, waited t ph1
//    pre-barrier ~ 1 full tile.  Tail: wrapped dummy stages, drained after
//    the loop.  Requires nt >= 3 (nt = 64 here).
// ============================================================================

__device__ __forceinline__ bf16x8 read_frag(const unsigned short* hb, int rowl, int slot) {
    int cs = slot ^ (rowl & 7);
    return *(const bf16x8*)(hb + rowl * 64 + (cs << 3));
}

__device__ __forceinline__ void stage_half(const unsigned short* __restrict__ G,
                                           int grow0, int K, int kbase,
                                           unsigned short* hb, int tid) {
    const int lane = tid & 63, wv = tid >> 6;
    #pragma unroll
    for (int j = 0; j < 2; ++j) {
        int u = j * 512 + wv * 64 + lane;            // 16B-unit 0..1023
        int rowl = u >> 3;
        int c = (u & 7) ^ (rowl & 7);                // inverse swizzle on source
        const unsigned short* g = G + (size_t)(grow0 + rowl) * K + kbase + c * 8;
        unsigned short* l = hb + (size_t)(j * 512 + wv * 64) * 8;  // wave-uniform
        __builtin_amdgcn_global_load_lds(
            (const __attribute__((address_space(1))) void*)g,
            (__attribute__((address_space(3))) void*)l, 16, 0, 0);
    }
}

__global__ __launch_bounds__(512, 2) void gemm_bt_bias(
    const unsigned short* __restrict__ A,   // bf16 bits [M,K]
    const unsigned short* __restrict__ B,   // bf16 bits [N,K] (weight)
    const float* __restrict__ bias,         // [N]
    float* __restrict__ C,                  // [M,N]
    int M, int N, int K)
{
    __shared__ unsigned short sA[2][2][8192];   // [dbuf][row-half][128*64]
    __shared__ unsigned short sB[2][2][8192];

    const int tid  = threadIdx.x;
    const int lane = tid & 63;
    const int wave = tid >> 6;
    const int wm = (wave >> 2) * 128;      // 2 waves along M
    const int wn = (wave & 3) * 64;        // 4 waves along N
    const int m32 = lane & 31;
    const int h   = lane >> 5;
    const int ah  = wm >> 7;               // wave's A row-half
    const int bh  = wn >> 7;               // wave's B row-half
    const int bro = wn & 64;               // row offset within B half

    // XCD-aware bijective remap (nwg = 512, %8 == 0)
    const int nbx = gridDim.x;
    const int nwg = gridDim.x * gridDim.y;
    int flat = blockIdx.y * gridDim.x + blockIdx.x;
    int rid = (nwg & 7) ? flat : ((flat & 7) * (nwg >> 3) + (flat >> 3));
    const int bm = (rid / nbx) * 256;
    const int bn = (rid % nbx) * 256;

    f32x16 acc[4][2];
    #pragma unroll
    for (int i = 0; i < 4; ++i)
        #pragma unroll
        for (int j = 0; j < 2; ++j)
            #pragma unroll
            for (int r = 0; r < 16; ++r) acc[i][j][r] = 0.f;

    // ---- prologue: tiles 0 and 1 for both operands ----
    stage_half(A, bm,       K, 0,  &sA[0][0][0], tid);
    stage_half(A, bm + 128, K, 0,  &sA[0][1][0], tid);
    stage_half(B, bn,       K, 0,  &sB[0][0][0], tid);
    stage_half(B, bn + 128, K, 0,  &sB[0][1][0], tid);
    stage_half(A, bm,       K, 64, &sA[1][0][0], tid);
    stage_half(A, bm + 128, K, 64, &sA[1][1][0], tid);
    stage_half(B, bn,       K, 64, &sB[1][0][0], tid);
    stage_half(B, bn + 128, K, 64, &sB[1][1][0], tid);
    asm volatile("s_waitcnt vmcnt(8)" ::: "memory");   // tile 0 landed
    __builtin_amdgcn_s_barrier();

    // fragment double buffers: X = current chunk0, Y = current chunk1
    bf16x8 Xa0[4], Xa1[4], Xb0[2], Xb1[2];
    bf16x8 Ya0[4], Ya1[4], Yb0[2], Yb1[2];

    // preload X = tile 0, chunk 0
    {
        const unsigned short* sAh = &sA[0][ah][0];
        const unsigned short* sBh = &sB[0][bh][0];
        #pragma unroll
        for (int i = 0; i < 4; ++i) {
            int rl = i * 32 + m32;
            Xa0[i] = read_frag(sAh, rl, h);
            Xa1[i] = read_frag(sAh, rl, 2 + h);
        }
        #pragma unroll
        for (int j = 0; j < 2; ++j) {
            int rl = bro + j * 32 + m32;
            Xb0[j] = read_frag(sBh, rl, h);
            Xb1[j] = read_frag(sBh, rl, 2 + h);
        }
    }

    const int nt = K >> 6;
    for (int t = 0; t < nt; ++t) {
        const int cur = t & 1, nxt = cur ^ 1;
        const int t2k = ((t + 2 < nt) ? t + 2 : 0) << 6;   // wrap = dummy
        const unsigned short* sAc = &sA[cur][ah][0];
        const unsigned short* sBc = &sB[cur][bh][0];
        const unsigned short* sAn = &sA[nxt][ah][0];
        const unsigned short* sBn = &sB[nxt][bh][0];

        // ===== ph0: prefetch Y (t, ch1), MFMA X (t, ch0) =====
        #pragma unroll
        for (int i = 0; i < 4; ++i) {
            int rl = i * 32 + m32;
            Ya0[i] = read_frag(sAc, rl, 4 + h);
            Ya1[i] = read_frag(sAc, rl, 6 + h);
        }
        #pragma unroll
        for (int j = 0; j < 2; ++j) {
            int rl = bro + j * 32 + m32;
            Yb0[j] = read_frag(sBc, rl, 4 + h);
            Yb1[j] = read_frag(sBc, rl, 6 + h);
        }
        __builtin_amdgcn_sched_barrier(0);
        __builtin_amdgcn_s_setprio(1);
        #pragma unroll
        for (int i = 0; i < 4; ++i)
            #pragma unroll
            for (int j = 0; j < 2; ++j)
                acc[i][j] = __builtin_amdgcn_mfma_f32_32x32x16_bf16(Xa0[i], Xb0[j], acc[i][j], 0, 0, 0);
        #pragma unroll
        for (int i = 0; i < 4; ++i)
            #pragma unroll
            for (int j = 0; j < 2; ++j)
                acc[i][j] = __builtin_amdgcn_mfma_f32_32x32x16_bf16(Xa1[i], Xb1[j], acc[i][j], 0, 0, 0);
        __builtin_amdgcn_s_setprio(0);

        // ===== ph1: barrier; prefetch X (t+1, ch0); stage t+2; MFMA Y =====
        asm volatile("s_waitcnt vmcnt(0) lgkmcnt(0)" ::: "memory");
        __builtin_amdgcn_sched_barrier(0);
        __builtin_amdgcn_s_barrier();
        #pragma unroll
        for (int i = 0; i < 4; ++i) {
            int rl = i * 32 + m32;
            Xa0[i] = read_frag(sAn, rl, h);
            Xa1[i] = read_frag(sAn, rl, 2 + h);
        }
        #pragma unroll
        for (int j = 0; j < 2; ++j) {
            int rl = bro + j * 32 + m32;
            Xb0[j] = read_frag(sBn, rl, h);
            Xb1[j] = read_frag(sBn, rl, 2 + h);
        }
        stage_half(A, bm,       K, t2k, &sA[cur][0][0], tid);
        stage_half(A, bm + 128, K, t2k, &sA[cur][1][0], tid);
        stage_half(B, bn,       K, t2k, &sB[cur][0][0], tid);
        stage_half(B, bn + 128, K, t2k, &sB[cur][1][0], tid);
        __builtin_amdgcn_sched_barrier(0);
        __builtin_amdgcn_s_setprio(1);
        #pragma unroll
        for (int i = 0; i < 4; ++i)
            #pragma unroll
            for (int j = 0; j < 2; ++j)
                acc[i][j] = __builtin_amdgcn_mfma_f32_32x32x16_bf16(Ya0[i], Yb0[j], acc[i][j], 0, 0, 0);
        #pragma unroll
        for (int i = 0; i < 4; ++i)
            #pragma unroll
            for (int j = 0; j < 2; ++j)
                acc[i][j] = __builtin_amdgcn_mfma_f32_32x32x16_bf16(Ya1[i], Yb1[j], acc[i][j], 0, 0, 0);
        __builtin_amdgcn_s_setprio(0);
    }
    asm volatile("s_waitcnt vmcnt(0)" ::: "memory");   // drain dummy tail DMAs

    // ---- epilogue: 32x32 C/D layout col=lane&31, row=(r&3)+8*(r>>2)+4*h ----
    #pragma unroll
    for (int j = 0; j < 2; ++j) {
        int col = bn + wn + j * 32 + m32;
        float bv = bias[col];
        #pragma unroll
        for (int i = 0; i < 4; ++i) {
            int rbase = bm + wm + i * 32 + 4 * h;
            #pragma unroll
            for (int r = 0; r < 16; ++r) {
                int row = rbase + (r & 3) + 8 * (r >> 2);
                __builtin_nontemporal_store(acc[i][j][r] + bv,
                                            &C[(size_t)row * N + col]);
            }
        }
    }
}

extern "C" void kernel_launch(void* const* d_in, const int* in_sizes, int n_in,
                              void* d_out, int out_size, void* d_ws, size_t ws_size,
                              hipStream_t stream) {
    const float* vals   = (const float*)d_in[0];
    const int*   rows   = (const int*)d_in[1];
    const int*   cols   = (const int*)d_in[2];
    const float* weight = (const float*)d_in[3];  // [OUT, IN] row-major
    const float* bias   = (const float*)d_in[4];

    const int NNZ = in_sizes[0];
    const int OUT = in_sizes[4];
    const int IN  = in_sizes[3] / OUT;
    const int M   = out_size / OUT;     // n_rows

    // workspace layout: Ab bf16 [M,IN] | Wb bf16 [OUT,IN]
    unsigned short* Ab = (unsigned short*)d_ws;
    size_t abBytes = (size_t)M * IN * sizeof(unsigned short);
    unsigned short* Wb = (unsigned short*)((char*)d_ws + abBytes);

    // 1) zero bf16 dense (bf16 zero == 0x0000)
    hipMemsetAsync(Ab, 0, abBytes, stream);

    // 2+3) fused scatter-add (pk_add_bf16) + weight convert
    {
        long nW = (long)OUT * IN;
        int cvtBlocks = (int)((nW / 8 + 255) / 256);
        int scBlocks  = (NNZ + 255) / 256;
        scatter_cvt<<<cvtBlocks + scBlocks, 256, 0, stream>>>(
            vals, rows, cols, Ab, NNZ, IN, weight, Wb, nW, cvtBlocks);
    }

    // 4) GEMM + bias (256x256 tiles, 512 threads)
    dim3 grid(OUT / 256, M / 256);   // 16 x 32 = 512 blocks
    gemm_bt_bias<<<grid, 512, 0, stream>>>(Ab, Wb, bias, (float*)d_out, M, OUT, IN);
}